// Round 1
// baseline (1285.095 us; speedup 1.0000x reference)
//
#include <hip/hip_runtime.h>

#define NU 100000      // N_USERS
#define NE 100000      // N_ENTITIES
#define NN 200000      // N_NODES
#define EKG 1500000
#define EPR 1500000
#define NNZI 1000000
#define D 64

#define GCN_ENT_BASE (NU * D)          // 6,400,000
#define NODE_BASE    (NN * D)          // 12,800,000

__device__ __forceinline__ float wave_sum_f(float v) {
    v += __shfl_xor(v, 32);
    v += __shfl_xor(v, 16);
    v += __shfl_xor(v, 8);
    v += __shfl_xor(v, 4);
    v += __shfl_xor(v, 2);
    v += __shfl_xor(v, 1);
    return v;
}

__device__ __forceinline__ int wave_sum_i(int v) {
    v += __shfl_xor(v, 32);
    v += __shfl_xor(v, 16);
    v += __shfl_xor(v, 8);
    v += __shfl_xor(v, 4);
    v += __shfl_xor(v, 2);
    v += __shfl_xor(v, 1);
    return v;
}

// ---------------- CSR build ----------------

__global__ void k_hist(const int* __restrict__ idx, int n, int* __restrict__ deg) {
    int i = blockIdx.x * blockDim.x + threadIdx.x;
    if (i < n) atomicAdd(&deg[idx[i]], 1);
}

// block of 256 threads sums a 1024-element chunk
__global__ void k_blocksum(const int* __restrict__ cnt, int n, int* __restrict__ bsum) {
    __shared__ int wsum[4];
    int base = blockIdx.x * 1024;
    int s = 0;
    for (int k = threadIdx.x; k < 1024; k += 256) {
        int i = base + k;
        s += (i < n) ? cnt[i] : 0;
    }
    s = wave_sum_i(s);
    int wid = threadIdx.x >> 6;
    if ((threadIdx.x & 63) == 0) wsum[wid] = s;
    __syncthreads();
    if (threadIdx.x == 0) bsum[blockIdx.x] = wsum[0] + wsum[1] + wsum[2] + wsum[3];
}

// single thread: exclusive scan of block sums (nb <= ~200), write total
__global__ void k_scansums(int* __restrict__ bsum, int nb, int* __restrict__ total_out) {
    if (blockIdx.x == 0 && threadIdx.x == 0) {
        int acc = 0;
        for (int b = 0; b < nb; b++) { int v = bsum[b]; bsum[b] = acc; acc += v; }
        *total_out = acc;
    }
}

// 1024 threads/block, Hillis-Steele exclusive scan of a 1024 chunk + block offset
__global__ void k_scanfinal(const int* __restrict__ cnt, const int* __restrict__ boff,
                            int n, int* __restrict__ off, int* __restrict__ cur) {
    __shared__ int buf[1024];
    int i = blockIdx.x * 1024 + threadIdx.x;
    int v = (i < n) ? cnt[i] : 0;
    int x = v;
    buf[threadIdx.x] = x;
    __syncthreads();
    for (int d = 1; d < 1024; d <<= 1) {
        int t = (threadIdx.x >= d) ? buf[threadIdx.x - d] : 0;
        __syncthreads();
        x += t;
        buf[threadIdx.x] = x;
        __syncthreads();
    }
    if (i < n) {
        int excl = x - v + boff[blockIdx.x];
        off[i] = excl;
        cur[i] = excl;
    }
}

__global__ void k_place_kg(const int* __restrict__ head, const int* __restrict__ tail,
                           const int* __restrict__ type, int n,
                           int* __restrict__ cur, int* __restrict__ csr) {
    int i = blockIdx.x * blockDim.x + threadIdx.x;
    if (i >= n) return;
    int h = head[i];
    int pos = atomicAdd(&cur[h], 1);
    csr[pos] = tail[i] | ((type[i] - 1) << 17);   // tail<2^17, rel 0..15
}

__global__ void k_place_pr(const int* __restrict__ head, const int* __restrict__ tail,
                           const int* __restrict__ type, int n,
                           int* __restrict__ cur, int* __restrict__ csr) {
    int i = blockIdx.x * blockDim.x + threadIdx.x;
    if (i >= n) return;
    int h = head[i];
    int pos = atomicAdd(&cur[h], 1);
    csr[pos] = tail[i] | (type[i] << 18);          // tail<2^18, type 0..31
}

__global__ void k_place_it(const int* __restrict__ rows, const int* __restrict__ cols,
                           const float* __restrict__ vals, int n,
                           int* __restrict__ cur, int* __restrict__ ccol, float* __restrict__ cval) {
    int i = blockIdx.x * blockDim.x + threadIdx.x;
    if (i >= n) return;
    int r = rows[i];
    int pos = atomicAdd(&cur[r], 1);
    ccol[pos] = cols[i];
    cval[pos] = vals[i];
}

// ---------------- output init ----------------
// user_res := user_emb ; node_res := concat(user_emb, entity_emb)
__global__ void k_init(const float* __restrict__ user, const float* __restrict__ ent,
                       float* __restrict__ out) {
    int i = blockIdx.x * blockDim.x + threadIdx.x;
    if (i >= NU * D) return;
    float u = user[i];
    float e = ent[i];
    out[i] = u;                            // gcn_res user part (user_res accumulator)
    out[NODE_BASE + i] = u;                // node_res user part
    out[NODE_BASE + NU * D + i] = e;       // node_res entity part
}

// ---------------- aggregation (one wave per destination row) ----------------

// entity_agg = scatter_mean(entity_src[tail]*weight[rel], head); raw + l2norm outputs
__global__ void k_agg_entity(const float* __restrict__ src, const float* __restrict__ w,
                             const int* __restrict__ off, const int* __restrict__ csr,
                             float* __restrict__ raw, float* __restrict__ nrm) {
    int lane = threadIdx.x & 63;
    int row = blockIdx.x * (blockDim.x >> 6) + (threadIdx.x >> 6);
    if (row >= NE) return;
    int s = off[row], e = off[row + 1];
    float acc = 0.f;
    for (int base = s; base < e; base += 64) {
        int m = e - base; if (m > 64) m = 64;
        int p = (lane < m) ? csr[base + lane] : 0;
        for (int k = 0; k < m; k++) {
            int pk = __shfl(p, k);
            int t = pk & 0x1FFFF;
            int r = pk >> 17;
            acc += src[t * D + lane] * w[r * D + lane];
        }
    }
    int cnt = e - s;
    float mean = acc / (float)(cnt > 1 ? cnt : 1);
    raw[row * D + lane] = mean;
    float n2 = wave_sum_f(mean * mean);
    float nr = fmaxf(sqrtf(n2), 1e-12f);
    nrm[row * D + lane] = mean / nr;
}

// node_agg = scatter_mean(all_embed[tail]*ew[type], head); l2norm, accumulate into node_res,
// optionally store normalized user rows for next hop's `u`
__global__ void k_agg_node(const float* __restrict__ u, const float* __restrict__ ent,
                           const float* __restrict__ ew,
                           const int* __restrict__ off, const int* __restrict__ csr,
                           float* __restrict__ node_res, float* __restrict__ u_out, int store_u) {
    int lane = threadIdx.x & 63;
    int row = blockIdx.x * (blockDim.x >> 6) + (threadIdx.x >> 6);
    if (row >= NN) return;
    int s = off[row], e = off[row + 1];
    float acc = 0.f;
    for (int base = s; base < e; base += 64) {
        int m = e - base; if (m > 64) m = 64;
        int p = (lane < m) ? csr[base + lane] : 0;
        for (int k = 0; k < m; k++) {
            int pk = __shfl(p, k);
            int t = pk & 0x3FFFF;
            int r = pk >> 18;
            const float* srow = (t < NU) ? (u + (size_t)t * D) : (ent + (size_t)(t - NU) * D);
            acc += srow[lane] * ew[r * D + lane];
        }
    }
    int cnt = e - s;
    float mean = acc / (float)(cnt > 1 ? cnt : 1);
    float n2 = wave_sum_f(mean * mean);
    float nr = fmaxf(sqrtf(n2), 1e-12f);
    float val = mean / nr;
    node_res[row * D + lane] += val;
    if (store_u && row < NU) u_out[row * D + lane] = val;
}

// user_new = segment_sum(val * ent_raw[col], row); l2norm, accumulate into user_res
__global__ void k_agg_user(const float* __restrict__ ent_raw,
                           const int* __restrict__ off, const int* __restrict__ ccol,
                           const float* __restrict__ cval, float* __restrict__ user_res) {
    int lane = threadIdx.x & 63;
    int row = blockIdx.x * (blockDim.x >> 6) + (threadIdx.x >> 6);
    if (row >= NU) return;
    int s = off[row], e = off[row + 1];
    float acc = 0.f;
    for (int base = s; base < e; base += 64) {
        int m = e - base; if (m > 64) m = 64;
        int c = (lane < m) ? ccol[base + lane] : 0;
        float v = (lane < m) ? cval[base + lane] : 0.f;
        for (int k = 0; k < m; k++) {
            int ck = __shfl(c, k);
            float vk = __shfl(v, k);
            acc += vk * ent_raw[ck * D + lane];
        }
    }
    float n2 = wave_sum_f(acc * acc);
    float nr = fmaxf(sqrtf(n2), 1e-12f);
    user_res[row * D + lane] += acc / nr;
}

extern "C" void kernel_launch(void* const* d_in, const int* in_sizes, int n_in,
                              void* d_out, int out_size, void* d_ws, size_t ws_size,
                              hipStream_t stream) {
    const float* user_emb     = (const float*)d_in[0];
    const float* entity_emb   = (const float*)d_in[1];
    const float* weight       = (const float*)d_in[2];
    const float* extra_weight = (const float*)d_in[3];
    const float* ivals        = (const float*)d_in[4];
    const int* edge_index     = (const int*)d_in[5];
    const int* edge_type      = (const int*)d_in[6];
    const int* xedge_index    = (const int*)d_in[7];
    const int* xedge_type     = (const int*)d_in[8];
    const int* interact_idx   = (const int*)d_in[9];
    float* out = (float*)d_out;

    const int* kg_head = edge_index;
    const int* kg_tail = edge_index + EKG;
    const int* pr_head = xedge_index;
    const int* pr_tail = xedge_index + EPR;
    const int* it_row  = interact_idx;
    const int* it_col  = interact_idx + NNZI;

    char* ws = (char*)d_ws;
    size_t ofs = 0;
    auto take = [&](size_t bytes) -> void* {
        void* p = ws + ofs;
        ofs += (bytes + 255) & ~(size_t)255;
        return p;
    };
    float* ent_raw = (float*)take((size_t)NE * D * 4);
    float* ent_nrm = (float*)take((size_t)NE * D * 4);
    float* uA      = (float*)take((size_t)NU * D * 4);
    int* off_kg = (int*)take((NE + 1) * 4);
    int* cur_kg = (int*)take((NE + 1) * 4);
    int* off_pr = (int*)take((NN + 1) * 4);
    int* cur_pr = (int*)take((NN + 1) * 4);
    int* off_it = (int*)take((NU + 1) * 4);
    int* cur_it = (int*)take((NU + 1) * 4);
    int* csr_kg = (int*)take((size_t)EKG * 4);
    int* csr_pr = (int*)take((size_t)EPR * 4);
    int* csr_ic = (int*)take((size_t)NNZI * 4);
    float* csr_iv = (float*)take((size_t)NNZI * 4);
    int* bsum = (int*)take(1024 * 4);

    // --- degree histograms (deg lives in cur_*) ---
    hipMemsetAsync(cur_kg, 0, (NE + 1) * 4, stream);
    hipMemsetAsync(cur_pr, 0, (NN + 1) * 4, stream);
    hipMemsetAsync(cur_it, 0, (NU + 1) * 4, stream);
    k_hist<<<(EKG + 255) / 256, 256, 0, stream>>>(kg_head, EKG, cur_kg);
    k_hist<<<(EPR + 255) / 256, 256, 0, stream>>>(pr_head, EPR, cur_pr);
    k_hist<<<(NNZI + 255) / 256, 256, 0, stream>>>(it_row, NNZI, cur_it);

    // --- exclusive scans -> off_*, cursors reset to off_* ---
    {
        int B = (NE + 1023) / 1024;
        k_blocksum<<<B, 256, 0, stream>>>(cur_kg, NE, bsum);
        k_scansums<<<1, 1, 0, stream>>>(bsum, B, off_kg + NE);
        k_scanfinal<<<B, 1024, 0, stream>>>(cur_kg, bsum, NE, off_kg, cur_kg);
    }
    {
        int B = (NN + 1023) / 1024;
        k_blocksum<<<B, 256, 0, stream>>>(cur_pr, NN, bsum);
        k_scansums<<<1, 1, 0, stream>>>(bsum, B, off_pr + NN);
        k_scanfinal<<<B, 1024, 0, stream>>>(cur_pr, bsum, NN, off_pr, cur_pr);
    }
    {
        int B = (NU + 1023) / 1024;
        k_blocksum<<<B, 256, 0, stream>>>(cur_it, NU, bsum);
        k_scansums<<<1, 1, 0, stream>>>(bsum, B, off_it + NU);
        k_scanfinal<<<B, 1024, 0, stream>>>(cur_it, bsum, NU, off_it, cur_it);
    }

    // --- CSR placement ---
    k_place_kg<<<(EKG + 255) / 256, 256, 0, stream>>>(kg_head, kg_tail, edge_type, EKG, cur_kg, csr_kg);
    k_place_pr<<<(EPR + 255) / 256, 256, 0, stream>>>(pr_head, pr_tail, xedge_type, EPR, cur_pr, csr_pr);
    k_place_it<<<(NNZI + 255) / 256, 256, 0, stream>>>(it_row, it_col, ivals, NNZI, cur_it, csr_ic, csr_iv);

    // --- init residual accumulators in d_out ---
    k_init<<<(NU * D + 255) / 256, 256, 0, stream>>>(user_emb, entity_emb, out);

    const int RPB = 4;  // rows (waves) per 256-thread block

    // --- hop 1 ---
    k_agg_entity<<<(NE + RPB - 1) / RPB, 256, 0, stream>>>(entity_emb, weight, off_kg, csr_kg, ent_raw, ent_nrm);
    k_agg_node<<<(NN + RPB - 1) / RPB, 256, 0, stream>>>(user_emb, entity_emb, extra_weight, off_pr, csr_pr,
                                                          out + NODE_BASE, uA, 1);
    k_agg_user<<<(NU + RPB - 1) / RPB, 256, 0, stream>>>(ent_raw, off_it, csr_ic, csr_iv, out);

    // --- hop 2 ---
    k_agg_entity<<<(NE + RPB - 1) / RPB, 256, 0, stream>>>(ent_nrm, weight, off_kg, csr_kg, ent_raw,
                                                            out + GCN_ENT_BASE);
    k_agg_node<<<(NN + RPB - 1) / RPB, 256, 0, stream>>>(uA, ent_nrm, extra_weight, off_pr, csr_pr,
                                                          out + NODE_BASE, nullptr, 0);
    k_agg_user<<<(NU + RPB - 1) / RPB, 256, 0, stream>>>(ent_raw, off_it, csr_ic, csr_iv, out);
}

// Round 2
// 968.923 us; speedup vs baseline: 1.3263x; 1.3263x over previous
//
#include <hip/hip_runtime.h>

#define NU 100000      // N_USERS
#define NE 100000      // N_ENTITIES
#define NN 200000      // N_NODES
#define EKG 1500000
#define EPR 1500000
#define NNZI 1000000
#define D 64

#define GCN_ENT_BASE (NU * D)
#define NODE_BASE    (NN * D)

// block counts for scans (1024-element chunks)
#define NB_KG 98     // ceil(NE/1024)
#define NB_PR 196    // ceil(NN/1024)
#define NB_IT 98     // ceil(NU/1024)
#define BS_KG 0
#define BS_PR 128
#define BS_IT 384

__device__ __forceinline__ float wave_sum_f(float v) {
    v += __shfl_xor(v, 32);
    v += __shfl_xor(v, 16);
    v += __shfl_xor(v, 8);
    v += __shfl_xor(v, 4);
    v += __shfl_xor(v, 2);
    v += __shfl_xor(v, 1);
    return v;
}

__device__ __forceinline__ int wave_sum_i(int v) {
    v += __shfl_xor(v, 32);
    v += __shfl_xor(v, 16);
    v += __shfl_xor(v, 8);
    v += __shfl_xor(v, 4);
    v += __shfl_xor(v, 2);
    v += __shfl_xor(v, 1);
    return v;
}

// ---------------- CSR build (fused) ----------------

__global__ void k_hist3(const int* __restrict__ kg_head, const int* __restrict__ pr_head,
                        const int* __restrict__ it_row,
                        int* __restrict__ deg_kg, int* __restrict__ deg_pr, int* __restrict__ deg_it) {
    int i = blockIdx.x * blockDim.x + threadIdx.x;
    if (i >= EKG) return;
    atomicAdd(&deg_kg[kg_head[i]], 1);
    atomicAdd(&deg_pr[pr_head[i]], 1);
    if (i < NNZI) atomicAdd(&deg_it[it_row[i]], 1);
}

// 392 blocks of 256 threads; each sums a 1024-element chunk of one of 3 arrays
__global__ void k_blocksum3(const int* __restrict__ ckg, const int* __restrict__ cpr,
                            const int* __restrict__ cit, int* __restrict__ bsum) {
    __shared__ int wsum[4];
    int bid = blockIdx.x;
    const int* cnt; int n; int* outp;
    if (bid < NB_KG)              { cnt = ckg; n = NE; outp = bsum + BS_KG + bid; }
    else if (bid < NB_KG + NB_PR) { bid -= NB_KG; cnt = cpr; n = NN; outp = bsum + BS_PR + bid; }
    else                          { bid -= NB_KG + NB_PR; cnt = cit; n = NU; outp = bsum + BS_IT + bid; }
    int base = bid * 1024;
    int s = 0;
    for (int k = threadIdx.x; k < 1024; k += 256) {
        int i = base + k;
        s += (i < n) ? cnt[i] : 0;
    }
    s = wave_sum_i(s);
    int wid = threadIdx.x >> 6;
    if ((threadIdx.x & 63) == 0) wsum[wid] = s;
    __syncthreads();
    if (threadIdx.x == 0) *outp = wsum[0] + wsum[1] + wsum[2] + wsum[3];
}

// 3 blocks of 1 thread; block b exclusive-scans its bsum segment, writes total
__global__ void k_scansums3(int* __restrict__ bsum, int* __restrict__ tkg,
                            int* __restrict__ tpr, int* __restrict__ tit) {
    if (threadIdx.x != 0) return;
    int* seg; int nb; int* tot;
    if (blockIdx.x == 0)      { seg = bsum + BS_KG; nb = NB_KG; tot = tkg; }
    else if (blockIdx.x == 1) { seg = bsum + BS_PR; nb = NB_PR; tot = tpr; }
    else                      { seg = bsum + BS_IT; nb = NB_IT; tot = tit; }
    int acc = 0;
    for (int b = 0; b < nb; b++) { int v = seg[b]; seg[b] = acc; acc += v; }
    *tot = acc;
}

// 392 blocks of 1024 threads; Hillis-Steele exclusive scan of 1024-chunk + block offset
__global__ void k_scanfinal3(const int* __restrict__ ckg, const int* __restrict__ cpr,
                             const int* __restrict__ cit, const int* __restrict__ bsum,
                             int* __restrict__ okg, int* __restrict__ opr, int* __restrict__ oit,
                             int* __restrict__ rkg, int* __restrict__ rpr, int* __restrict__ rit) {
    __shared__ int buf[1024];
    int bid = blockIdx.x;
    const int* cnt; int n; const int* boff; int* off; int* cur;
    if (bid < NB_KG)              { cnt = ckg; n = NE; boff = bsum + BS_KG; off = okg; cur = rkg; }
    else if (bid < NB_KG + NB_PR) { bid -= NB_KG; cnt = cpr; n = NN; boff = bsum + BS_PR; off = opr; cur = rpr; }
    else                          { bid -= NB_KG + NB_PR; cnt = cit; n = NU; boff = bsum + BS_IT; off = oit; cur = rit; }
    int i = bid * 1024 + threadIdx.x;
    int v = (i < n) ? cnt[i] : 0;
    int x = v;
    buf[threadIdx.x] = x;
    __syncthreads();
    for (int d = 1; d < 1024; d <<= 1) {
        int t = (threadIdx.x >= d) ? buf[threadIdx.x - d] : 0;
        __syncthreads();
        x += t;
        buf[threadIdx.x] = x;
        __syncthreads();
    }
    if (i < n) {
        int excl = x - v + boff[bid];
        off[i] = excl;
        cur[i] = excl;
    }
}

__global__ void k_place3(const int* __restrict__ kg_head, const int* __restrict__ kg_tail,
                         const int* __restrict__ kg_type,
                         const int* __restrict__ pr_head, const int* __restrict__ pr_tail,
                         const int* __restrict__ pr_type,
                         const int* __restrict__ it_row, const int* __restrict__ it_col,
                         const float* __restrict__ it_val,
                         int* __restrict__ cur_kg, int* __restrict__ cur_pr, int* __restrict__ cur_it,
                         int* __restrict__ csr_kg, int* __restrict__ csr_pr,
                         int* __restrict__ csr_ic, float* __restrict__ csr_iv) {
    int i = blockIdx.x * blockDim.x + threadIdx.x;
    if (i >= EKG) return;
    {
        int pos = atomicAdd(&cur_kg[kg_head[i]], 1);
        csr_kg[pos] = kg_tail[i] | ((kg_type[i] - 1) << 17);   // tail<2^17, rel 0..15
    }
    {
        int pos = atomicAdd(&cur_pr[pr_head[i]], 1);
        csr_pr[pos] = pr_tail[i] | (pr_type[i] << 18);          // tail<2^18, type 0..31
    }
    if (i < NNZI) {
        int pos = atomicAdd(&cur_it[it_row[i]], 1);
        csr_ic[pos] = it_col[i];
        csr_iv[pos] = it_val[i];
    }
}

// ---------------- output init ----------------
__global__ void k_init(const float* __restrict__ user, const float* __restrict__ ent,
                       float* __restrict__ out) {
    int i = blockIdx.x * blockDim.x + threadIdx.x;
    if (i >= NU * D) return;
    float u = user[i];
    float e = ent[i];
    out[i] = u;                            // user_res accumulator
    out[NODE_BASE + i] = u;                // node_res user part
    out[NODE_BASE + NU * D + i] = e;       // node_res entity part
}

// ---------------- aggregation ----------------
// Wave layout: 4 edge-subgroups (sub = lane>>4) x 16 lanes (d4 = lane&15),
// each lane handles one float4 (4 dims) of the 64-dim row. 8 edges in flight
// per serial step (two independent chains per subgroup).

__global__ void k_agg_entity(const float4* __restrict__ src, const float4* __restrict__ w,
                             const int* __restrict__ off, const int* __restrict__ csr,
                             float4* __restrict__ raw, float4* __restrict__ nrm) {
    int lane = threadIdx.x & 63;
    int sub = lane >> 4, d4 = lane & 15;
    int row = blockIdx.x * (blockDim.x >> 6) + (threadIdx.x >> 6);
    if (row >= NE) return;
    int s = off[row], e = off[row + 1];
    float4 acc = make_float4(0.f, 0.f, 0.f, 0.f);
    for (int base = s; base < e; base += 64) {
        int m = e - base; if (m > 64) m = 64;
        int p = (lane < m) ? csr[base + lane] : 0;
        int kmax = (m + 7) >> 3;
        for (int k = 0; k < kmax; k++) {
            int ei0 = (k << 3) + sub;
            int ei1 = ei0 + 4;
            int pk0 = __shfl(p, ei0);
            int pk1 = __shfl(p, ei1);
            if (ei0 < m) {
                int t = pk0 & 0x1FFFF, r = pk0 >> 17;
                float4 sv = src[t * 16 + d4];
                float4 wv = w[r * 16 + d4];
                acc.x += sv.x * wv.x; acc.y += sv.y * wv.y;
                acc.z += sv.z * wv.z; acc.w += sv.w * wv.w;
            }
            if (ei1 < m) {
                int t = pk1 & 0x1FFFF, r = pk1 >> 17;
                float4 sv = src[t * 16 + d4];
                float4 wv = w[r * 16 + d4];
                acc.x += sv.x * wv.x; acc.y += sv.y * wv.y;
                acc.z += sv.z * wv.z; acc.w += sv.w * wv.w;
            }
        }
    }
    // reduce across the 4 edge-subgroups
    acc.x += __shfl_xor(acc.x, 16); acc.x += __shfl_xor(acc.x, 32);
    acc.y += __shfl_xor(acc.y, 16); acc.y += __shfl_xor(acc.y, 32);
    acc.z += __shfl_xor(acc.z, 16); acc.z += __shfl_xor(acc.z, 32);
    acc.w += __shfl_xor(acc.w, 16); acc.w += __shfl_xor(acc.w, 32);
    int cnt = e - s;
    float invc = 1.f / (float)(cnt > 1 ? cnt : 1);
    float4 mean = make_float4(acc.x * invc, acc.y * invc, acc.z * invc, acc.w * invc);
    float local = mean.x * mean.x + mean.y * mean.y + mean.z * mean.z + mean.w * mean.w;
    float n2 = wave_sum_f(local) * 0.25f;   // each dim counted 4x (replicated subs)
    float inr = 1.f / fmaxf(sqrtf(n2), 1e-12f);
    if (sub == 0) {
        raw[row * 16 + d4] = mean;
        nrm[row * 16 + d4] = make_float4(mean.x * inr, mean.y * inr, mean.z * inr, mean.w * inr);
    }
}

__global__ void k_agg_node(const float4* __restrict__ u, const float4* __restrict__ ent,
                           const float4* __restrict__ ew,
                           const int* __restrict__ off, const int* __restrict__ csr,
                           float4* __restrict__ node_res, float4* __restrict__ u_out, int store_u) {
    int lane = threadIdx.x & 63;
    int sub = lane >> 4, d4 = lane & 15;
    int row = blockIdx.x * (blockDim.x >> 6) + (threadIdx.x >> 6);
    if (row >= NN) return;
    int s = off[row], e = off[row + 1];
    float4 acc = make_float4(0.f, 0.f, 0.f, 0.f);
    for (int base = s; base < e; base += 64) {
        int m = e - base; if (m > 64) m = 64;
        int p = (lane < m) ? csr[base + lane] : 0;
        int kmax = (m + 7) >> 3;
        for (int k = 0; k < kmax; k++) {
            int ei0 = (k << 3) + sub;
            int ei1 = ei0 + 4;
            int pk0 = __shfl(p, ei0);
            int pk1 = __shfl(p, ei1);
            if (ei0 < m) {
                int t = pk0 & 0x3FFFF, r = pk0 >> 18;
                const float4* srow = (t < NU) ? (u + (size_t)t * 16) : (ent + (size_t)(t - NU) * 16);
                float4 sv = srow[d4];
                float4 wv = ew[r * 16 + d4];
                acc.x += sv.x * wv.x; acc.y += sv.y * wv.y;
                acc.z += sv.z * wv.z; acc.w += sv.w * wv.w;
            }
            if (ei1 < m) {
                int t = pk1 & 0x3FFFF, r = pk1 >> 18;
                const float4* srow = (t < NU) ? (u + (size_t)t * 16) : (ent + (size_t)(t - NU) * 16);
                float4 sv = srow[d4];
                float4 wv = ew[r * 16 + d4];
                acc.x += sv.x * wv.x; acc.y += sv.y * wv.y;
                acc.z += sv.z * wv.z; acc.w += sv.w * wv.w;
            }
        }
    }
    acc.x += __shfl_xor(acc.x, 16); acc.x += __shfl_xor(acc.x, 32);
    acc.y += __shfl_xor(acc.y, 16); acc.y += __shfl_xor(acc.y, 32);
    acc.z += __shfl_xor(acc.z, 16); acc.z += __shfl_xor(acc.z, 32);
    acc.w += __shfl_xor(acc.w, 16); acc.w += __shfl_xor(acc.w, 32);
    int cnt = e - s;
    float invc = 1.f / (float)(cnt > 1 ? cnt : 1);
    float4 mean = make_float4(acc.x * invc, acc.y * invc, acc.z * invc, acc.w * invc);
    float local = mean.x * mean.x + mean.y * mean.y + mean.z * mean.z + mean.w * mean.w;
    float n2 = wave_sum_f(local) * 0.25f;
    float inr = 1.f / fmaxf(sqrtf(n2), 1e-12f);
    if (sub == 0) {
        float4 val = make_float4(mean.x * inr, mean.y * inr, mean.z * inr, mean.w * inr);
        float4 o = node_res[row * 16 + d4];
        o.x += val.x; o.y += val.y; o.z += val.z; o.w += val.w;
        node_res[row * 16 + d4] = o;
        if (store_u && row < NU) u_out[row * 16 + d4] = val;
    }
}

__global__ void k_agg_user(const float4* __restrict__ ent_raw,
                           const int* __restrict__ off, const int* __restrict__ ccol,
                           const float* __restrict__ cval, float4* __restrict__ user_res) {
    int lane = threadIdx.x & 63;
    int sub = lane >> 4, d4 = lane & 15;
    int row = blockIdx.x * (blockDim.x >> 6) + (threadIdx.x >> 6);
    if (row >= NU) return;
    int s = off[row], e = off[row + 1];
    float4 acc = make_float4(0.f, 0.f, 0.f, 0.f);
    for (int base = s; base < e; base += 64) {
        int m = e - base; if (m > 64) m = 64;
        int c = (lane < m) ? ccol[base + lane] : 0;
        float v = (lane < m) ? cval[base + lane] : 0.f;
        int kmax = (m + 7) >> 3;
        for (int k = 0; k < kmax; k++) {
            int ei0 = (k << 3) + sub;
            int ei1 = ei0 + 4;
            int c0 = __shfl(c, ei0);
            float v0 = __shfl(v, ei0);
            int c1 = __shfl(c, ei1);
            float v1 = __shfl(v, ei1);
            if (ei0 < m) {
                float4 sv = ent_raw[c0 * 16 + d4];
                acc.x += v0 * sv.x; acc.y += v0 * sv.y;
                acc.z += v0 * sv.z; acc.w += v0 * sv.w;
            }
            if (ei1 < m) {
                float4 sv = ent_raw[c1 * 16 + d4];
                acc.x += v1 * sv.x; acc.y += v1 * sv.y;
                acc.z += v1 * sv.z; acc.w += v1 * sv.w;
            }
        }
    }
    acc.x += __shfl_xor(acc.x, 16); acc.x += __shfl_xor(acc.x, 32);
    acc.y += __shfl_xor(acc.y, 16); acc.y += __shfl_xor(acc.y, 32);
    acc.z += __shfl_xor(acc.z, 16); acc.z += __shfl_xor(acc.z, 32);
    acc.w += __shfl_xor(acc.w, 16); acc.w += __shfl_xor(acc.w, 32);
    float local = acc.x * acc.x + acc.y * acc.y + acc.z * acc.z + acc.w * acc.w;
    float n2 = wave_sum_f(local) * 0.25f;
    float inr = 1.f / fmaxf(sqrtf(n2), 1e-12f);
    if (sub == 0) {
        float4 o = user_res[row * 16 + d4];
        o.x += acc.x * inr; o.y += acc.y * inr;
        o.z += acc.z * inr; o.w += acc.w * inr;
        user_res[row * 16 + d4] = o;
    }
}

extern "C" void kernel_launch(void* const* d_in, const int* in_sizes, int n_in,
                              void* d_out, int out_size, void* d_ws, size_t ws_size,
                              hipStream_t stream) {
    const float* user_emb     = (const float*)d_in[0];
    const float* entity_emb   = (const float*)d_in[1];
    const float* weight       = (const float*)d_in[2];
    const float* extra_weight = (const float*)d_in[3];
    const float* ivals        = (const float*)d_in[4];
    const int* edge_index     = (const int*)d_in[5];
    const int* edge_type      = (const int*)d_in[6];
    const int* xedge_index    = (const int*)d_in[7];
    const int* xedge_type     = (const int*)d_in[8];
    const int* interact_idx   = (const int*)d_in[9];
    float* out = (float*)d_out;

    const int* kg_head = edge_index;
    const int* kg_tail = edge_index + EKG;
    const int* pr_head = xedge_index;
    const int* pr_tail = xedge_index + EPR;
    const int* it_row  = interact_idx;
    const int* it_col  = interact_idx + NNZI;

    char* ws = (char*)d_ws;
    size_t ofs = 0;
    auto take = [&](size_t bytes) -> void* {
        void* p = ws + ofs;
        ofs += (bytes + 255) & ~(size_t)255;
        return p;
    };
    float* ent_raw = (float*)take((size_t)NE * D * 4);
    float* ent_nrm = (float*)take((size_t)NE * D * 4);
    float* uA      = (float*)take((size_t)NU * D * 4);
    int* off_kg = (int*)take((NE + 1) * 4);
    int* off_pr = (int*)take((NN + 1) * 4);
    int* off_it = (int*)take((NU + 1) * 4);
    int* curs   = (int*)take((size_t)(NE + NN + NU + 3) * 4);
    int* cur_kg = curs;
    int* cur_pr = curs + (NE + 1);
    int* cur_it = curs + (NE + 1) + (NN + 1);
    int* csr_kg = (int*)take((size_t)EKG * 4);
    int* csr_pr = (int*)take((size_t)EPR * 4);
    int* csr_ic = (int*)take((size_t)NNZI * 4);
    float* csr_iv = (float*)take((size_t)NNZI * 4);
    int* bsum = (int*)take(512 * 4);

    // degree histograms (into cur_*) — one fused memset + one fused kernel
    hipMemsetAsync(curs, 0, (size_t)(NE + NN + NU + 3) * 4, stream);
    k_hist3<<<(EKG + 255) / 256, 256, 0, stream>>>(kg_head, pr_head, it_row, cur_kg, cur_pr, cur_it);

    // exclusive scans -> off_*, cursors reset to off_*
    k_blocksum3<<<NB_KG + NB_PR + NB_IT, 256, 0, stream>>>(cur_kg, cur_pr, cur_it, bsum);
    k_scansums3<<<3, 1, 0, stream>>>(bsum, off_kg + NE, off_pr + NN, off_it + NU);
    k_scanfinal3<<<NB_KG + NB_PR + NB_IT, 1024, 0, stream>>>(cur_kg, cur_pr, cur_it, bsum,
                                                             off_kg, off_pr, off_it,
                                                             cur_kg, cur_pr, cur_it);

    // CSR placement (fused)
    k_place3<<<(EKG + 255) / 256, 256, 0, stream>>>(kg_head, kg_tail, edge_type,
                                                    pr_head, pr_tail, xedge_type,
                                                    it_row, it_col, ivals,
                                                    cur_kg, cur_pr, cur_it,
                                                    csr_kg, csr_pr, csr_ic, csr_iv);

    // init residual accumulators in d_out
    k_init<<<(NU * D + 255) / 256, 256, 0, stream>>>(user_emb, entity_emb, out);

    const int RPB = 4;  // waves (rows) per 256-thread block

    const float4* user4 = (const float4*)user_emb;
    const float4* ent4  = (const float4*)entity_emb;
    const float4* w4    = (const float4*)weight;
    const float4* ew4   = (const float4*)extra_weight;

    // hop 1
    k_agg_entity<<<(NE + RPB - 1) / RPB, 256, 0, stream>>>(ent4, w4, off_kg, csr_kg,
                                                           (float4*)ent_raw, (float4*)ent_nrm);
    k_agg_node<<<(NN + RPB - 1) / RPB, 256, 0, stream>>>(user4, ent4, ew4, off_pr, csr_pr,
                                                         (float4*)(out + NODE_BASE), (float4*)uA, 1);
    k_agg_user<<<(NU + RPB - 1) / RPB, 256, 0, stream>>>((const float4*)ent_raw, off_it, csr_ic, csr_iv,
                                                         (float4*)out);

    // hop 2
    k_agg_entity<<<(NE + RPB - 1) / RPB, 256, 0, stream>>>((const float4*)ent_nrm, w4, off_kg, csr_kg,
                                                           (float4*)ent_raw, (float4*)(out + GCN_ENT_BASE));
    k_agg_node<<<(NN + RPB - 1) / RPB, 256, 0, stream>>>((const float4*)uA, (const float4*)ent_nrm, ew4,
                                                         off_pr, csr_pr,
                                                         (float4*)(out + NODE_BASE), nullptr, 0);
    k_agg_user<<<(NU + RPB - 1) / RPB, 256, 0, stream>>>((const float4*)ent_raw, off_it, csr_ic, csr_iv,
                                                         (float4*)out);
}